// Round 1
// baseline (397.975 us; speedup 1.0000x reference)
//
#include <hip/hip_runtime.h>
#include <hip/hip_bf16.h>

typedef __bf16 bf16;
typedef __bf16 bf16x4 __attribute__((ext_vector_type(4)));
typedef __bf16 bf16x8 __attribute__((ext_vector_type(8)));
typedef float f32x4 __attribute__((ext_vector_type(4)));

#define NH 16
#define HD 64
#define SEQ 2048
#define DM 1024
#define MTOT 4096   // B*S

__device__ __forceinline__ void gload_lds16(const void* g, void* l) {
  __builtin_amdgcn_global_load_lds(
      (const __attribute__((address_space(1))) void*)g,
      (__attribute__((address_space(3))) void*)l, 16, 0, 0);
}

// ---------------- fp32 -> bf16 conversion (vectorized) ----------------
__global__ void cvt_kernel(const float* __restrict__ in, bf16* __restrict__ out, int n4) {
  int i = blockIdx.x * blockDim.x + threadIdx.x;
  if (i >= n4) return;
  float4 v = reinterpret_cast<const float4*>(in)[i];
  bf16x4 o;
  o[0] = (bf16)v.x; o[1] = (bf16)v.y; o[2] = (bf16)v.z; o[3] = (bf16)v.w;
  *reinterpret_cast<bf16x4*>(out + (size_t)i * 4) = o;
}

// ---------------- RoPE cos/sin table: tab[m][i2] = (cos, sin) ----------------
__global__ void rope_tab_kernel(const int* __restrict__ pos, float2* __restrict__ tab) {
  int i = blockIdx.x * blockDim.x + threadIdx.x;
  if (i >= MTOT * 32) return;
  int m = i >> 5, i2 = i & 31;
  float pf = (float)pos[m];
  float inv = 1.0f / powf(10000.0f, (float)(2 * i2) * (1.0f / 64.0f));
  float a = pf * inv;
  tab[i] = make_float2(cosf(a), sinf(a));
}

// ---------------- 128x128-tile bf16 GEMM, C = A * Bw^T ----------------
// MODE 0: Q proj (RoPE epilogue, write [B,H,S,hd] bf16)
// MODE 1: K proj (same)
// MODE 2: V proj (write transposed [B,H,hd,S] bf16)
// MODE 3: out proj (A read from att [B,H,S,hd] layout, write fp32 [M,DM])
template<int MODE>
__global__ __launch_bounds__(256) void gemm_bt(
    const bf16* __restrict__ A, const bf16* __restrict__ Bw,
    bf16* __restrict__ outb, float* __restrict__ outf,
    const float2* __restrict__ tab)
{
  __shared__ bf16 As[128 * 32];
  __shared__ bf16 Bs[128 * 32];
  const int t = threadIdx.x;
  const int w = t >> 6;
  const int lane = t & 63;
  const int lr = lane & 15;
  const int lg = lane >> 4;
  const int lk = lg << 3;
  const int m0 = blockIdx.y * 128;
  const int n0 = blockIdx.x * 128;
  const int wr = w >> 1, wc = w & 1;

  f32x4 acc[4][4] = {};

  for (int k0 = 0; k0 < DM; k0 += 32) {
#pragma unroll
    for (int pp = 0; pp < 2; ++pp) {
      int chunk = pp * 256 + t;
      int r = chunk >> 2;
      int c = (chunk & 3) << 3;
      const bf16* ga;
      if constexpr (MODE == 3) {
        int m = m0 + r;
        int kk = k0 + c;
        ga = A + (((size_t)((m >> 11) * NH + (kk >> 6)) * SEQ + (m & 2047)) * HD + (kk & 63));
      } else {
        ga = A + (size_t)(m0 + r) * DM + k0 + c;
      }
      gload_lds16(ga, (char*)As + (pp * 256 + w * 64) * 16);
      const bf16* gb = Bw + (size_t)(n0 + r) * DM + k0 + c;
      gload_lds16(gb, (char*)Bs + (pp * 256 + w * 64) * 16);
    }
    __syncthreads();
    bf16x8 af[4], bfr[4];
#pragma unroll
    for (int f = 0; f < 4; ++f) {
      af[f]  = *reinterpret_cast<const bf16x8*>(As + (wr * 64 + f * 16 + lr) * 32 + lk);
      bfr[f] = *reinterpret_cast<const bf16x8*>(Bs + (wc * 64 + f * 16 + lr) * 32 + lk);
    }
#pragma unroll
    for (int i = 0; i < 4; ++i)
#pragma unroll
      for (int j = 0; j < 4; ++j)
        acc[i][j] = __builtin_amdgcn_mfma_f32_16x16x32_bf16(af[i], bfr[j], acc[i][j], 0, 0, 0);
    __syncthreads();
  }

  if constexpr (MODE == 0 || MODE == 1) {
#pragma unroll
    for (int j = 0; j < 4; ++j) {
      int n = n0 + wc * 64 + j * 16 + lr;
      int h = n >> 6, d = n & 63;
      int i2 = d >> 1;
      bool odd = d & 1;
#pragma unroll
      for (int i = 0; i < 4; ++i) {
#pragma unroll
        for (int rr = 0; rr < 4; ++rr) {
          int m = m0 + wr * 64 + i * 16 + lg * 4 + rr;
          float v = acc[i][j][rr];
          float o = __shfl_xor(v, 1);
          float2 cs = tab[(m << 5) + i2];
          float res = odd ? (v * cs.x + o * cs.y) : (v * cs.x - o * cs.y);
          outb[((size_t)((m >> 11) * NH + h) * SEQ + (m & 2047)) * HD + d] = (bf16)res;
        }
      }
    }
  } else if constexpr (MODE == 2) {
#pragma unroll
    for (int j = 0; j < 4; ++j) {
      int n = n0 + wc * 64 + j * 16 + lr;
      int h = n >> 6, d = n & 63;
#pragma unroll
      for (int i = 0; i < 4; ++i) {
#pragma unroll
        for (int rr = 0; rr < 4; ++rr) {
          int m = m0 + wr * 64 + i * 16 + lg * 4 + rr;
          outb[((size_t)((m >> 11) * NH + h) * HD + d) * SEQ + (m & 2047)] = (bf16)acc[i][j][rr];
        }
      }
    }
  } else {
#pragma unroll
    for (int j = 0; j < 4; ++j) {
      int n = n0 + wc * 64 + j * 16 + lr;
#pragma unroll
      for (int i = 0; i < 4; ++i) {
#pragma unroll
        for (int rr = 0; rr < 4; ++rr) {
          int m = m0 + wr * 64 + i * 16 + lg * 4 + rr;
          outf[(size_t)m * DM + n] = acc[i][j][rr];
        }
      }
    }
  }
}

// ---------------- flash attention ----------------
// grid (S/64, B*H), block 256. Wave w handles 16 q-rows.
// q,k: [B,H,S,hd] bf16.  vt: [B,H,hd,S] bf16.  att out: [B,H,S,hd] bf16.
__global__ __launch_bounds__(256) void attn_kernel(
    const bf16* __restrict__ q, const bf16* __restrict__ k,
    const bf16* __restrict__ vt, bf16* __restrict__ att)
{
  __shared__ bf16 plds[4 * 16 * 72];  // per-wave P buffer, stride 72 (pad vs bank conflict)
  const int t = threadIdx.x;
  const int w = t >> 6;
  const int lane = t & 63;
  const int lr = lane & 15;
  const int lg = lane >> 4;
  const int lk = lg << 3;
  const int bh = blockIdx.y;
  const int qblk = blockIdx.x * 64;
  const int q0 = qblk + w * 16;

  const bf16* qb = q + (size_t)bh * SEQ * HD;
  const bf16* kb = k + (size_t)bh * SEQ * HD;
  const bf16* vb = vt + (size_t)bh * HD * SEQ;
  bf16* pl = plds + w * (16 * 72);

  bf16x8 qf[2];
  qf[0] = *reinterpret_cast<const bf16x8*>(qb + (size_t)(q0 + lr) * HD + lk);
  qf[1] = *reinterpret_cast<const bf16x8*>(qb + (size_t)(q0 + lr) * HD + lk + 32);

  f32x4 acc[4] = {};
  float mrow[4] = {-1e30f, -1e30f, -1e30f, -1e30f};
  float lrow[4] = {0.f, 0.f, 0.f, 0.f};

  for (int kv0 = 0; kv0 <= qblk; kv0 += 64) {
    // ---- scores: S = Q K^T * 0.125 ----
    f32x4 sc[4];
#pragma unroll
    for (int cg = 0; cg < 4; ++cg) {
      bf16x8 kf0 = *reinterpret_cast<const bf16x8*>(kb + (size_t)(kv0 + cg * 16 + lr) * HD + lk);
      bf16x8 kf1 = *reinterpret_cast<const bf16x8*>(kb + (size_t)(kv0 + cg * 16 + lr) * HD + lk + 32);
      f32x4 z = {0.f, 0.f, 0.f, 0.f};
      z = __builtin_amdgcn_mfma_f32_16x16x32_bf16(qf[0], kf0, z, 0, 0, 0);
      z = __builtin_amdgcn_mfma_f32_16x16x32_bf16(qf[1], kf1, z, 0, 0, 0);
      sc[cg] = z;
    }
    // ---- scale + causal mask ----
#pragma unroll
    for (int cg = 0; cg < 4; ++cg)
#pragma unroll
      for (int rr = 0; rr < 4; ++rr) {
        float s = sc[cg][rr] * 0.125f;
        if (kv0 + cg * 16 + lr > q0 + lg * 4 + rr) s = -1e30f;
        sc[cg][rr] = s;
      }
    // ---- online softmax ----
    float mx[4];
#pragma unroll
    for (int rr = 0; rr < 4; ++rr) {
      float a = fmaxf(fmaxf(sc[0][rr], sc[1][rr]), fmaxf(sc[2][rr], sc[3][rr]));
#pragma unroll
      for (int off = 1; off < 16; off <<= 1) a = fmaxf(a, __shfl_xor(a, off));
      mx[rr] = a;
    }
    float oscale[4];
#pragma unroll
    for (int rr = 0; rr < 4; ++rr) {
      float mn = fmaxf(mrow[rr], mx[rr]);
      oscale[rr] = __expf(mrow[rr] - mn);
      mrow[rr] = mn;
    }
    float psum[4] = {0.f, 0.f, 0.f, 0.f};
#pragma unroll
    for (int cg = 0; cg < 4; ++cg)
#pragma unroll
      for (int rr = 0; rr < 4; ++rr) {
        float p = __expf(sc[cg][rr] - mrow[rr]);
        sc[cg][rr] = p;
        psum[rr] += p;
      }
#pragma unroll
    for (int rr = 0; rr < 4; ++rr) {
      float a = psum[rr];
#pragma unroll
      for (int off = 1; off < 16; off <<= 1) a += __shfl_xor(a, off);
      lrow[rr] = lrow[rr] * oscale[rr] + a;
    }
#pragma unroll
    for (int fn = 0; fn < 4; ++fn)
#pragma unroll
      for (int rr = 0; rr < 4; ++rr) acc[fn][rr] *= oscale[rr];

    // ---- P -> LDS (C-layout scatter), read back as A-fragments ----
    __syncthreads();
#pragma unroll
    for (int cg = 0; cg < 4; ++cg)
#pragma unroll
      for (int rr = 0; rr < 4; ++rr)
        pl[(lg * 4 + rr) * 72 + cg * 16 + lr] = (bf16)sc[cg][rr];
    __syncthreads();
    bf16x8 pf0 = *reinterpret_cast<const bf16x8*>(pl + lr * 72 + lk);
    bf16x8 pf1 = *reinterpret_cast<const bf16x8*>(pl + lr * 72 + 32 + lk);
    // ---- PV ----
#pragma unroll
    for (int fn = 0; fn < 4; ++fn) {
      const bf16* vrow = vb + (size_t)(fn * 16 + lr) * SEQ + kv0;
      bf16x8 v0 = *reinterpret_cast<const bf16x8*>(vrow + lk);
      bf16x8 v1 = *reinterpret_cast<const bf16x8*>(vrow + 32 + lk);
      acc[fn] = __builtin_amdgcn_mfma_f32_16x16x32_bf16(pf0, v0, acc[fn], 0, 0, 0);
      acc[fn] = __builtin_amdgcn_mfma_f32_16x16x32_bf16(pf1, v1, acc[fn], 0, 0, 0);
    }
  }

  // ---- normalize + write ----
#pragma unroll
  for (int fn = 0; fn < 4; ++fn)
#pragma unroll
    for (int rr = 0; rr < 4; ++rr) {
      float o = acc[fn][rr] / lrow[rr];
      att[((size_t)bh * SEQ + q0 + lg * 4 + rr) * HD + fn * 16 + lr] = (bf16)o;
    }
}

extern "C" void kernel_launch(void* const* d_in, const int* in_sizes, int n_in,
                              void* d_out, int out_size, void* d_ws, size_t ws_size,
                              hipStream_t stream) {
  const float* x  = (const float*)d_in[0];
  const int* pos  = (const int*)d_in[1];
  const float* Wq = (const float*)d_in[2];
  const float* Wk = (const float*)d_in[3];
  const float* Wv = (const float*)d_in[4];
  const float* Wo = (const float*)d_in[5];
  float* out = (float*)d_out;

  char* p = (char*)d_ws;
  bf16* xb   = (bf16*)p; p += (size_t)MTOT * DM * 2;
  bf16* wqb  = (bf16*)p; p += (size_t)DM * DM * 2;
  bf16* wkb  = (bf16*)p; p += (size_t)DM * DM * 2;
  bf16* wvb  = (bf16*)p; p += (size_t)DM * DM * 2;
  bf16* wob  = (bf16*)p; p += (size_t)DM * DM * 2;
  bf16* qb   = (bf16*)p; p += (size_t)MTOT * DM * 2;
  bf16* kb   = (bf16*)p; p += (size_t)MTOT * DM * 2;
  bf16* vtb  = (bf16*)p; p += (size_t)MTOT * DM * 2;
  bf16* attb = (bf16*)p; p += (size_t)MTOT * DM * 2;
  float2* tab = (float2*)p; p += (size_t)MTOT * 32 * sizeof(float2);

  cvt_kernel<<<(MTOT * DM / 4 + 255) / 256, 256, 0, stream>>>(x, xb, MTOT * DM / 4);
  cvt_kernel<<<(DM * DM / 4 + 255) / 256, 256, 0, stream>>>(Wq, wqb, DM * DM / 4);
  cvt_kernel<<<(DM * DM / 4 + 255) / 256, 256, 0, stream>>>(Wk, wkb, DM * DM / 4);
  cvt_kernel<<<(DM * DM / 4 + 255) / 256, 256, 0, stream>>>(Wv, wvb, DM * DM / 4);
  cvt_kernel<<<(DM * DM / 4 + 255) / 256, 256, 0, stream>>>(Wo, wob, DM * DM / 4);
  rope_tab_kernel<<<(MTOT * 32 + 255) / 256, 256, 0, stream>>>(pos, tab);

  dim3 g(DM / 128, MTOT / 128);
  gemm_bt<0><<<g, 256, 0, stream>>>(xb, wqb, qb, nullptr, tab);
  gemm_bt<1><<<g, 256, 0, stream>>>(xb, wkb, kb, nullptr, tab);
  gemm_bt<2><<<g, 256, 0, stream>>>(xb, wvb, vtb, nullptr, nullptr);

  attn_kernel<<<dim3(SEQ / 64, 2 * NH), 256, 0, stream>>>(qb, kb, vtb, attb);

  gemm_bt<3><<<g, 256, 0, stream>>>(attb, wob, nullptr, out, nullptr);
}

// Round 2
// 188.241 us; speedup vs baseline: 2.1142x; 2.1142x over previous
//
#include <hip/hip_runtime.h>
#include <hip/hip_bf16.h>

typedef __bf16 bf16;
typedef __bf16 bf16x4 __attribute__((ext_vector_type(4)));
typedef __bf16 bf16x8 __attribute__((ext_vector_type(8)));
typedef float f32x4 __attribute__((ext_vector_type(4)));

#define NH 16
#define HD 64
#define SEQ 2048
#define DM 1024
#define MTOT 4096   // B*S

__device__ __forceinline__ void gload_lds16(const void* g, void* l) {
  __builtin_amdgcn_global_load_lds(
      (const __attribute__((address_space(1))) void*)g,
      (__attribute__((address_space(3))) void*)l, 16, 0, 0);
}

// ---------------- fp32 -> bf16 conversion (vectorized) ----------------
__global__ void cvt_kernel(const float* __restrict__ in, bf16* __restrict__ out, int n4) {
  int i = blockIdx.x * blockDim.x + threadIdx.x;
  if (i >= n4) return;
  float4 v = reinterpret_cast<const float4*>(in)[i];
  bf16x4 o;
  o[0] = (bf16)v.x; o[1] = (bf16)v.y; o[2] = (bf16)v.z; o[3] = (bf16)v.w;
  *reinterpret_cast<bf16x4*>(out + (size_t)i * 4) = o;
}

// ---------------- RoPE cos/sin table: tab[m][i2] = (cos, sin) ----------------
__global__ void rope_tab_kernel(const int* __restrict__ pos, float2* __restrict__ tab) {
  int i = blockIdx.x * blockDim.x + threadIdx.x;
  if (i >= MTOT * 32) return;
  int m = i >> 5, i2 = i & 31;
  float pf = (float)pos[m];
  float inv = 1.0f / powf(10000.0f, (float)(2 * i2) * (1.0f / 64.0f));
  float a = pf * inv;
  tab[i] = make_float2(cosf(a), sinf(a));
}

// ---------------- 128x128-tile bf16 GEMM, C = A * Bw^T ----------------
// MODE 0: Q proj (RoPE epilogue + 1/8 scale, write [B,H,S,hd] bf16)
// MODE 1: K proj (RoPE epilogue, write [B,H,S,hd] bf16)
// MODE 2: V proj (write transposed [B,H,hd,S] bf16)
// MODE 3: out proj (A read from att [B,H,S,hd] layout, write fp32 [M,DM])
template<int MODE>
__global__ __launch_bounds__(256) void gemm_bt(
    const bf16* __restrict__ A, const bf16* __restrict__ Bw,
    bf16* __restrict__ outb, float* __restrict__ outf,
    const float2* __restrict__ tab)
{
  __shared__ bf16 As[128 * 32];
  __shared__ bf16 Bs[128 * 32];
  const int t = threadIdx.x;
  const int w = t >> 6;
  const int lane = t & 63;
  const int lr = lane & 15;
  const int lg = lane >> 4;
  const int lk = lg << 3;
  const int m0 = blockIdx.y * 128;
  const int n0 = blockIdx.x * 128;
  const int wr = w >> 1, wc = w & 1;

  f32x4 acc[4][4] = {};

  for (int k0 = 0; k0 < DM; k0 += 32) {
#pragma unroll
    for (int pp = 0; pp < 2; ++pp) {
      int chunk = pp * 256 + t;
      int r = chunk >> 2;
      int c = (chunk & 3) << 3;
      const bf16* ga;
      if constexpr (MODE == 3) {
        int m = m0 + r;
        int kk = k0 + c;
        ga = A + (((size_t)((m >> 11) * NH + (kk >> 6)) * SEQ + (m & 2047)) * HD + (kk & 63));
      } else {
        ga = A + (size_t)(m0 + r) * DM + k0 + c;
      }
      gload_lds16(ga, (char*)As + (pp * 256 + w * 64) * 16);
      const bf16* gb = Bw + (size_t)(n0 + r) * DM + k0 + c;
      gload_lds16(gb, (char*)Bs + (pp * 256 + w * 64) * 16);
    }
    __syncthreads();
    bf16x8 af[4], bfr[4];
#pragma unroll
    for (int f = 0; f < 4; ++f) {
      af[f]  = *reinterpret_cast<const bf16x8*>(As + (wr * 64 + f * 16 + lr) * 32 + lk);
      bfr[f] = *reinterpret_cast<const bf16x8*>(Bs + (wc * 64 + f * 16 + lr) * 32 + lk);
    }
#pragma unroll
    for (int i = 0; i < 4; ++i)
#pragma unroll
      for (int j = 0; j < 4; ++j)
        acc[i][j] = __builtin_amdgcn_mfma_f32_16x16x32_bf16(af[i], bfr[j], acc[i][j], 0, 0, 0);
    __syncthreads();
  }

  if constexpr (MODE == 0 || MODE == 1) {
#pragma unroll
    for (int j = 0; j < 4; ++j) {
      int n = n0 + wc * 64 + j * 16 + lr;
      int h = n >> 6, d = n & 63;
      int i2 = d >> 1;
      bool odd = d & 1;
#pragma unroll
      for (int i = 0; i < 4; ++i) {
#pragma unroll
        for (int rr = 0; rr < 4; ++rr) {
          int m = m0 + wr * 64 + i * 16 + lg * 4 + rr;
          float v = acc[i][j][rr];
          float o = __shfl_xor(v, 1);
          float2 cs = tab[(m << 5) + i2];
          float res = odd ? (v * cs.x + o * cs.y) : (v * cs.x - o * cs.y);
          if constexpr (MODE == 0) res *= 0.125f;  // fold 1/sqrt(hd) into Q
          outb[((size_t)((m >> 11) * NH + h) * SEQ + (m & 2047)) * HD + d] = (bf16)res;
        }
      }
    }
  } else if constexpr (MODE == 2) {
#pragma unroll
    for (int j = 0; j < 4; ++j) {
      int n = n0 + wc * 64 + j * 16 + lr;
      int h = n >> 6, d = n & 63;
#pragma unroll
      for (int i = 0; i < 4; ++i) {
#pragma unroll
        for (int rr = 0; rr < 4; ++rr) {
          int m = m0 + wr * 64 + i * 16 + lg * 4 + rr;
          outb[((size_t)((m >> 11) * NH + h) * HD + d) * SEQ + (m & 2047)] = (bf16)acc[i][j][rr];
        }
      }
    }
  } else {
#pragma unroll
    for (int j = 0; j < 4; ++j) {
      int n = n0 + wc * 64 + j * 16 + lr;
#pragma unroll
      for (int i = 0; i < 4; ++i) {
#pragma unroll
        for (int rr = 0; rr < 4; ++rr) {
          int m = m0 + wr * 64 + i * 16 + lg * 4 + rr;
          outf[(size_t)m * DM + n] = acc[i][j][rr];
        }
      }
    }
  }
}

// ---------------- flash attention, LDS-staged K/V, paired strips ----------------
// grid (16, B*H), block 256 (4 waves x 16 q-rows). Block handles q-strips j and 31-j.
// q,k: [B,H,S,hd] bf16 (Q pre-scaled by 1/8). vt: [B,H,hd,S] bf16. att: [B,H,S,hd] bf16.

// stage one 64x64 bf16 tile (linear LDS [64 rows][128 B], source pre-swizzled so
// read-side byte^((row&7)<<4) yields the true (row,col) element).
__device__ __forceinline__ void stage_tile(const char* gRow0, size_t rowStrideB, int colByte0,
                                           char* lds, int t) {
#pragma unroll
  for (int p = 0; p < 2; ++p) {
    int o = (p * 256 + t) * 16;
    int r = o >> 7;
    int cb = o & 127;
    int cbs = cb ^ ((r & 7) << 4);
    gload_lds16(gRow0 + (size_t)r * rowStrideB + colByte0 + cbs, lds + o);
  }
}

__device__ __forceinline__ bf16x8 frag64(const char* tile, int row, int colByte) {
  int b = row * 128 + (colByte ^ ((row & 7) << 4));
  return *reinterpret_cast<const bf16x8*>(tile + b);
}

__global__ __launch_bounds__(256) void attn_kernel(
    const bf16* __restrict__ q, const bf16* __restrict__ k,
    const bf16* __restrict__ vt, bf16* __restrict__ att)
{
  __shared__ bf16 Ks[2][64 * 64];
  __shared__ bf16 Vs[2][64 * 64];
  __shared__ bf16 plds[4 * 16 * 72];
  const int t = threadIdx.x;
  const int w = t >> 6;
  const int lane = t & 63;
  const int lr = lane & 15;
  const int lg = lane >> 4;
  const int lk = lg << 3;
  const int bh = blockIdx.y;

  const bf16* qb = q + (size_t)bh * SEQ * HD;
  const char* kbB = (const char*)(k + (size_t)bh * SEQ * HD);
  const char* vbB = (const char*)(vt + (size_t)bh * HD * SEQ);
  bf16* pl = plds + w * (16 * 72);

  for (int sidx = 0; sidx < 2; ++sidx) {
    const int strip = sidx ? (31 - (int)blockIdx.x) : (int)blockIdx.x;
    const int q0 = strip * 64 + w * 16;
    const int ntile = strip + 1;

    bf16x8 qf0 = *reinterpret_cast<const bf16x8*>(qb + (size_t)(q0 + lr) * HD + lk);
    bf16x8 qf1 = *reinterpret_cast<const bf16x8*>(qb + (size_t)(q0 + lr) * HD + lk + 32);

    f32x4 acc[4] = {};
    float mrow[4] = {-1e30f, -1e30f, -1e30f, -1e30f};
    float lrow[4] = {0.f, 0.f, 0.f, 0.f};

    // prologue: stage tile 0 into buffer 0
    stage_tile(kbB, 128, 0, (char*)Ks[0], t);
    stage_tile(vbB, 4096, 0, (char*)Vs[0], t);
    __syncthreads();

    for (int it = 0; it < ntile; ++it) {
      const int kv0 = it * 64;
      const int cur = it & 1;
      // issue next-tile stage before compute (loads fly under the MFMAs)
      if (it + 1 < ntile) {
        stage_tile(kbB + (size_t)(kv0 + 64) * 128, 128, 0, (char*)Ks[cur ^ 1], t);
        stage_tile(vbB, 4096, (kv0 + 64) * 2, (char*)Vs[cur ^ 1], t);
      }
      const char* Kt = (const char*)Ks[cur];
      const char* Vt = (const char*)Vs[cur];

      // ---- scores: S = (Q/8) K^T ----
      f32x4 sc[4];
#pragma unroll
      for (int cg = 0; cg < 4; ++cg) {
        bf16x8 kf0 = frag64(Kt, cg * 16 + lr, lg * 16);
        bf16x8 kf1 = frag64(Kt, cg * 16 + lr, 64 + lg * 16);
        f32x4 z = {0.f, 0.f, 0.f, 0.f};
        z = __builtin_amdgcn_mfma_f32_16x16x32_bf16(qf0, kf0, z, 0, 0, 0);
        z = __builtin_amdgcn_mfma_f32_16x16x32_bf16(qf1, kf1, z, 0, 0, 0);
        sc[cg] = z;
      }
      // ---- causal mask (diagonal tile only) ----
      if (it == ntile - 1) {
#pragma unroll
        for (int cg = 0; cg < 4; ++cg)
#pragma unroll
          for (int rr = 0; rr < 4; ++rr)
            if (kv0 + cg * 16 + lr > q0 + lg * 4 + rr) sc[cg][rr] = -1e30f;
      }
      // ---- online softmax ----
      float mx[4];
#pragma unroll
      for (int rr = 0; rr < 4; ++rr) {
        float a = fmaxf(fmaxf(sc[0][rr], sc[1][rr]), fmaxf(sc[2][rr], sc[3][rr]));
#pragma unroll
        for (int off = 1; off < 16; off <<= 1) a = fmaxf(a, __shfl_xor(a, off));
        mx[rr] = a;
      }
      float oscale[4];
#pragma unroll
      for (int rr = 0; rr < 4; ++rr) {
        float mn = fmaxf(mrow[rr], mx[rr]);
        oscale[rr] = __expf(mrow[rr] - mn);
        mrow[rr] = mn;
      }
      float psum[4] = {0.f, 0.f, 0.f, 0.f};
#pragma unroll
      for (int cg = 0; cg < 4; ++cg)
#pragma unroll
        for (int rr = 0; rr < 4; ++rr) {
          float p = __expf(sc[cg][rr] - mrow[rr]);
          sc[cg][rr] = p;
          psum[rr] += p;
        }
#pragma unroll
      for (int rr = 0; rr < 4; ++rr) {
        float a = psum[rr];
#pragma unroll
        for (int off = 1; off < 16; off <<= 1) a += __shfl_xor(a, off);
        lrow[rr] = lrow[rr] * oscale[rr] + a;
      }
#pragma unroll
      for (int fn = 0; fn < 4; ++fn)
#pragma unroll
        for (int rr = 0; rr < 4; ++rr) acc[fn][rr] *= oscale[rr];

      // ---- P -> per-wave LDS (C-layout scatter) -> A-fragments (no barrier: wave-private) ----
#pragma unroll
      for (int cg = 0; cg < 4; ++cg)
#pragma unroll
        for (int rr = 0; rr < 4; ++rr)
          pl[(lg * 4 + rr) * 72 + cg * 16 + lr] = (bf16)sc[cg][rr];
      bf16x8 pf0 = *reinterpret_cast<const bf16x8*>(pl + lr * 72 + lk);
      bf16x8 pf1 = *reinterpret_cast<const bf16x8*>(pl + lr * 72 + 32 + lk);

      // ---- PV ----
#pragma unroll
      for (int fn = 0; fn < 4; ++fn) {
        bf16x8 v0 = frag64(Vt, fn * 16 + lr, lg * 16);
        bf16x8 v1 = frag64(Vt, fn * 16 + lr, 64 + lg * 16);
        acc[fn] = __builtin_amdgcn_mfma_f32_16x16x32_bf16(pf0, v0, acc[fn], 0, 0, 0);
        acc[fn] = __builtin_amdgcn_mfma_f32_16x16x32_bf16(pf1, v1, acc[fn], 0, 0, 0);
      }
      __syncthreads();
    }

    // ---- normalize + write ----
#pragma unroll
    for (int fn = 0; fn < 4; ++fn)
#pragma unroll
      for (int rr = 0; rr < 4; ++rr) {
        float o = acc[fn][rr] / lrow[rr];
        att[((size_t)bh * SEQ + q0 + lg * 4 + rr) * HD + fn * 16 + lr] = (bf16)o;
      }
  }
}

extern "C" void kernel_launch(void* const* d_in, const int* in_sizes, int n_in,
                              void* d_out, int out_size, void* d_ws, size_t ws_size,
                              hipStream_t stream) {
  const float* x  = (const float*)d_in[0];
  const int* pos  = (const int*)d_in[1];
  const float* Wq = (const float*)d_in[2];
  const float* Wk = (const float*)d_in[3];
  const float* Wv = (const float*)d_in[4];
  const float* Wo = (const float*)d_in[5];
  float* out = (float*)d_out;

  char* p = (char*)d_ws;
  bf16* xb   = (bf16*)p; p += (size_t)MTOT * DM * 2;
  bf16* wqb  = (bf16*)p; p += (size_t)DM * DM * 2;
  bf16* wkb  = (bf16*)p; p += (size_t)DM * DM * 2;
  bf16* wvb  = (bf16*)p; p += (size_t)DM * DM * 2;
  bf16* wob  = (bf16*)p; p += (size_t)DM * DM * 2;
  bf16* qb   = (bf16*)p; p += (size_t)MTOT * DM * 2;
  bf16* kb   = (bf16*)p; p += (size_t)MTOT * DM * 2;
  bf16* vtb  = (bf16*)p; p += (size_t)MTOT * DM * 2;
  bf16* attb = (bf16*)p; p += (size_t)MTOT * DM * 2;
  float2* tab = (float2*)p; p += (size_t)MTOT * 32 * sizeof(float2);

  cvt_kernel<<<(MTOT * DM / 4 + 255) / 256, 256, 0, stream>>>(x, xb, MTOT * DM / 4);
  cvt_kernel<<<(DM * DM / 4 + 255) / 256, 256, 0, stream>>>(Wq, wqb, DM * DM / 4);
  cvt_kernel<<<(DM * DM / 4 + 255) / 256, 256, 0, stream>>>(Wk, wkb, DM * DM / 4);
  cvt_kernel<<<(DM * DM / 4 + 255) / 256, 256, 0, stream>>>(Wv, wvb, DM * DM / 4);
  cvt_kernel<<<(DM * DM / 4 + 255) / 256, 256, 0, stream>>>(Wo, wob, DM * DM / 4);
  rope_tab_kernel<<<(MTOT * 32 + 255) / 256, 256, 0, stream>>>(pos, tab);

  dim3 g(DM / 128, MTOT / 128);
  gemm_bt<0><<<g, 256, 0, stream>>>(xb, wqb, qb, nullptr, tab);
  gemm_bt<1><<<g, 256, 0, stream>>>(xb, wkb, kb, nullptr, tab);
  gemm_bt<2><<<g, 256, 0, stream>>>(xb, wvb, vtb, nullptr, nullptr);

  attn_kernel<<<dim3(16, 2 * NH), 256, 0, stream>>>(qb, kb, vtb, attb);

  gemm_bt<3><<<g, 256, 0, stream>>>(attb, wob, nullptr, out, nullptr);
}

// Round 3
// 174.592 us; speedup vs baseline: 2.2795x; 1.0782x over previous
//
#include <hip/hip_runtime.h>
#include <hip/hip_bf16.h>

typedef __bf16 bf16;
typedef __bf16 bf16x4 __attribute__((ext_vector_type(4)));
typedef __bf16 bf16x8 __attribute__((ext_vector_type(8)));
typedef float f32x4 __attribute__((ext_vector_type(4)));
typedef float f32x16 __attribute__((ext_vector_type(16)));
typedef unsigned int u32x4 __attribute__((ext_vector_type(4)));

#define NH 16
#define HD 64
#define SEQ 2048
#define DM 1024
#define MTOT 4096   // B*S

__device__ __forceinline__ void gload_lds16(const void* g, void* l) {
  __builtin_amdgcn_global_load_lds(
      (const __attribute__((address_space(1))) void*)g,
      (__attribute__((address_space(3))) void*)l, 16, 0, 0);
}

// ---------------- fp32 -> bf16 conversion (vectorized) ----------------
__global__ void cvt_kernel(const float* __restrict__ in, bf16* __restrict__ out, int n4) {
  int i = blockIdx.x * blockDim.x + threadIdx.x;
  if (i >= n4) return;
  float4 v = reinterpret_cast<const float4*>(in)[i];
  bf16x4 o;
  o[0] = (bf16)v.x; o[1] = (bf16)v.y; o[2] = (bf16)v.z; o[3] = (bf16)v.w;
  *reinterpret_cast<bf16x4*>(out + (size_t)i * 4) = o;
}

// 4 weight matrices (1M elems each) -> contiguous bf16 out
__global__ void cvt4_kernel(const float* __restrict__ w0, const float* __restrict__ w1,
                            const float* __restrict__ w2, const float* __restrict__ w3,
                            bf16* __restrict__ out) {
  int i = blockIdx.x * blockDim.x + threadIdx.x;   // 0 .. 4*262144-1
  int seg = i >> 18;
  int j = i & 262143;
  const float* src = seg == 0 ? w0 : seg == 1 ? w1 : seg == 2 ? w2 : w3;
  float4 v = reinterpret_cast<const float4*>(src)[j];
  bf16x4 o;
  o[0] = (bf16)v.x; o[1] = (bf16)v.y; o[2] = (bf16)v.z; o[3] = (bf16)v.w;
  *reinterpret_cast<bf16x4*>(out + ((size_t)seg << 20) + (size_t)j * 4) = o;
}

// ---------------- RoPE cos/sin table: tab[m][i2] = (cos, sin) ----------------
__global__ void rope_tab_kernel(const int* __restrict__ pos, float2* __restrict__ tab) {
  int i = blockIdx.x * blockDim.x + threadIdx.x;
  if (i >= MTOT * 32) return;
  int m = i >> 5, i2 = i & 31;
  float pf = (float)pos[m];
  float inv = 1.0f / powf(10000.0f, (float)(2 * i2) * (1.0f / 64.0f));
  float a = pf * inv;
  tab[i] = make_float2(cosf(a), sinf(a));
}

// ---------------- fused QKV projection GEMM ----------------
// blockIdx.x in 0..23: proj = x>>3 (0=Q,1=K,2=V), n0 = (x&7)*128.
// Q: RoPE + 0.125 scale -> [B,H,S,hd]; K: RoPE -> [B,H,S,hd]; V: -> [B,H,hd,S]
__global__ __launch_bounds__(256) void gemm_qkv(
    const bf16* __restrict__ A, const bf16* __restrict__ wq,
    const bf16* __restrict__ wk, const bf16* __restrict__ wv,
    bf16* __restrict__ outq, bf16* __restrict__ outk, bf16* __restrict__ outv,
    const float2* __restrict__ tab)
{
  __shared__ bf16 As[128 * 32];
  __shared__ bf16 Bs[128 * 32];
  const int t = threadIdx.x;
  const int w = t >> 6;
  const int lane = t & 63;
  const int lr = lane & 15;
  const int lg = lane >> 4;
  const int lk = lg << 3;
  const int m0 = blockIdx.y * 128;
  const int proj = blockIdx.x >> 3;
  const int n0 = (blockIdx.x & 7) * 128;
  const bf16* Bw = proj == 0 ? wq : proj == 1 ? wk : wv;
  const int wr = w >> 1, wc = w & 1;

  f32x4 acc[4][4] = {};

  for (int k0 = 0; k0 < DM; k0 += 32) {
#pragma unroll
    for (int pp = 0; pp < 2; ++pp) {
      int chunk = pp * 256 + t;
      int r = chunk >> 2;
      int c = (chunk & 3) << 3;
      gload_lds16(A + (size_t)(m0 + r) * DM + k0 + c, (char*)As + (pp * 256 + w * 64) * 16);
      gload_lds16(Bw + (size_t)(n0 + r) * DM + k0 + c, (char*)Bs + (pp * 256 + w * 64) * 16);
    }
    __syncthreads();
    bf16x8 af[4], bfr[4];
#pragma unroll
    for (int f = 0; f < 4; ++f) {
      af[f]  = *reinterpret_cast<const bf16x8*>(As + (wr * 64 + f * 16 + lr) * 32 + lk);
      bfr[f] = *reinterpret_cast<const bf16x8*>(Bs + (wc * 64 + f * 16 + lr) * 32 + lk);
    }
#pragma unroll
    for (int i = 0; i < 4; ++i)
#pragma unroll
      for (int j = 0; j < 4; ++j)
        acc[i][j] = __builtin_amdgcn_mfma_f32_16x16x32_bf16(af[i], bfr[j], acc[i][j], 0, 0, 0);
    __syncthreads();
  }

  if (proj < 2) {
    bf16* outb = proj ? outk : outq;
#pragma unroll
    for (int j = 0; j < 4; ++j) {
      int n = n0 + wc * 64 + j * 16 + lr;
      int h = n >> 6, d = n & 63;
      int i2 = d >> 1;
      bool odd = d & 1;
#pragma unroll
      for (int i = 0; i < 4; ++i) {
#pragma unroll
        for (int rr = 0; rr < 4; ++rr) {
          int m = m0 + wr * 64 + i * 16 + lg * 4 + rr;
          float v = acc[i][j][rr];
          float o = __shfl_xor(v, 1);
          float2 cs = tab[(m << 5) + i2];
          float res = odd ? (v * cs.x + o * cs.y) : (v * cs.x - o * cs.y);
          if (proj == 0) res *= 0.125f;
          outb[((size_t)((m >> 11) * NH + h) * SEQ + (m & 2047)) * HD + d] = (bf16)res;
        }
      }
    }
  } else {
#pragma unroll
    for (int j = 0; j < 4; ++j) {
      int n = n0 + wc * 64 + j * 16 + lr;
      int h = n >> 6, d = n & 63;
#pragma unroll
      for (int i = 0; i < 4; ++i) {
#pragma unroll
        for (int rr = 0; rr < 4; ++rr) {
          int m = m0 + wr * 64 + i * 16 + lg * 4 + rr;
          outv[((size_t)((m >> 11) * NH + h) * HD + d) * SEQ + (m & 2047)] = (bf16)acc[i][j][rr];
        }
      }
    }
  }
}

// ---------------- output projection GEMM (A from att [B,H,S,hd]) ----------------
__global__ __launch_bounds__(256) void gemm_out(
    const bf16* __restrict__ A, const bf16* __restrict__ Bw, float* __restrict__ outf)
{
  __shared__ bf16 As[128 * 32];
  __shared__ bf16 Bs[128 * 32];
  const int t = threadIdx.x;
  const int w = t >> 6;
  const int lane = t & 63;
  const int lr = lane & 15;
  const int lg = lane >> 4;
  const int lk = lg << 3;
  const int m0 = blockIdx.y * 128;
  const int n0 = blockIdx.x * 128;
  const int wr = w >> 1, wc = w & 1;

  f32x4 acc[4][4] = {};

  for (int k0 = 0; k0 < DM; k0 += 32) {
#pragma unroll
    for (int pp = 0; pp < 2; ++pp) {
      int chunk = pp * 256 + t;
      int r = chunk >> 2;
      int c = (chunk & 3) << 3;
      int m = m0 + r;
      int kk = k0 + c;
      const bf16* ga = A + (((size_t)((m >> 11) * NH + (kk >> 6)) * SEQ + (m & 2047)) * HD + (kk & 63));
      gload_lds16(ga, (char*)As + (pp * 256 + w * 64) * 16);
      gload_lds16(Bw + (size_t)(n0 + r) * DM + k0 + c, (char*)Bs + (pp * 256 + w * 64) * 16);
    }
    __syncthreads();
    bf16x8 af[4], bfr[4];
#pragma unroll
    for (int f = 0; f < 4; ++f) {
      af[f]  = *reinterpret_cast<const bf16x8*>(As + (wr * 64 + f * 16 + lr) * 32 + lk);
      bfr[f] = *reinterpret_cast<const bf16x8*>(Bs + (wc * 64 + f * 16 + lr) * 32 + lk);
    }
#pragma unroll
    for (int i = 0; i < 4; ++i)
#pragma unroll
      for (int j = 0; j < 4; ++j)
        acc[i][j] = __builtin_amdgcn_mfma_f32_16x16x32_bf16(af[i], bfr[j], acc[i][j], 0, 0, 0);
    __syncthreads();
  }

#pragma unroll
  for (int j = 0; j < 4; ++j) {
    int n = n0 + wc * 64 + j * 16 + lr;
#pragma unroll
    for (int i = 0; i < 4; ++i) {
#pragma unroll
      for (int rr = 0; rr < 4; ++rr) {
        int m = m0 + wr * 64 + i * 16 + lg * 4 + rr;
        outf[(size_t)m * DM + n] = acc[i][j][rr];
      }
    }
  }
}

// ---------------- flash attention, swapped-operand 32x32, in-register softmax ----
// grid (16, B*H), block 256 (4 waves x 32 q-rows). Waves 0,1: strip x; waves 2,3:
// strip 31-x (64-row strips); both consume one shared staged K/V tile stream.
__device__ __forceinline__ void stage_tile(const char* gRow0, size_t rowStrideB, int colByte0,
                                           char* lds, int t) {
#pragma unroll
  for (int p = 0; p < 2; ++p) {
    int o = (p * 256 + t) * 16;
    int r = o >> 7;
    int cb = o & 127;
    int cbs = cb ^ ((r & 7) << 4);
    gload_lds16(gRow0 + (size_t)r * rowStrideB + colByte0 + cbs, lds + o);
  }
}

__device__ __forceinline__ bf16x8 frag64(const char* tile, int row, int colByte) {
  int b = row * 128 + (colByte ^ ((row & 7) << 4));
  return *reinterpret_cast<const bf16x8*>(tile + b);
}

__device__ __forceinline__ unsigned packw(float a, float b) {
  unsigned short la = __builtin_bit_cast(unsigned short, (bf16)a);
  unsigned short lb = __builtin_bit_cast(unsigned short, (bf16)b);
  return (unsigned)la | ((unsigned)lb << 16);
}

__global__ __launch_bounds__(256) void attn_kernel(
    const bf16* __restrict__ q, const bf16* __restrict__ k,
    const bf16* __restrict__ vt, bf16* __restrict__ att)
{
  __shared__ bf16 Ks[2][64 * 64];
  __shared__ bf16 Vs[2][64 * 64];
  const int t = threadIdx.x;
  const int w = t >> 6;
  const int lane = t & 63;
  const int l31 = lane & 31;
  const int h = lane >> 5;
  const int bh = blockIdx.y;
  const int x = blockIdx.x;

  const int strip = (w < 2) ? x : 31 - x;          // 64-row strip index
  const int myN = strip + 1;                        // kv tiles this wave needs
  const int blkN = 32 - x;                          // tiles staged by the block
  const int q0w = strip * 64 + (w & 1) * 32;        // this wave's 32 q-rows

  const bf16* qb = q + (size_t)bh * SEQ * HD;
  const char* kbB = (const char*)(k + (size_t)bh * SEQ * HD);
  const char* vbB = (const char*)(vt + (size_t)bh * HD * SEQ);

  // Q fragments (B operand of 32x32x16): qf[s] = Q[q0w+l31][s*16 + h*8 .. +7]
  bf16x8 qf[4];
#pragma unroll
  for (int s = 0; s < 4; ++s)
    qf[s] = *reinterpret_cast<const bf16x8*>(qb + (size_t)(q0w + l31) * HD + s * 16 + h * 8);

  f32x16 acc0 = {}, acc1 = {};
  float mrow = -1e30f, lrow = 0.f;

  stage_tile(kbB, 128, 0, (char*)Ks[0], t);
  stage_tile(vbB, 4096, 0, (char*)Vs[0], t);
  __syncthreads();

  for (int it = 0; it < blkN; ++it) {
    const int cur = it & 1;
    if (it + 1 < blkN) {
      stage_tile(kbB + (size_t)(it + 1) * 8192, 128, 0, (char*)Ks[cur ^ 1], t);
      stage_tile(vbB, 4096, (it + 1) * 128, (char*)Vs[cur ^ 1], t);
    }
    if (it < myN) {
      const char* Kt = (const char*)Ks[cur];
      // ---- S^T = mfma(K, Q): lane holds S[q=q0w+l31][kv 32 values] ----
      f32x16 s0 = {}, s1 = {};
#pragma unroll
      for (int s = 0; s < 4; ++s) {
        bf16x8 kf0 = frag64(Kt, l31, s * 32 + h * 16);
        bf16x8 kf1 = frag64(Kt, 32 + l31, s * 32 + h * 16);
        s0 = __builtin_amdgcn_mfma_f32_32x32x16_bf16(kf0, qf[s], s0, 0, 0, 0);
        s1 = __builtin_amdgcn_mfma_f32_32x32x16_bf16(kf1, qf[s], s1, 0, 0, 0);
      }
      // ---- causal mask (diagonal tile only): kv_local > q_local ----
      if (it == strip) {
        int qloc = (w & 1) * 32 + l31;
#pragma unroll
        for (int reg = 0; reg < 16; ++reg) {
          int ro = (reg & 3) + 8 * (reg >> 2) + 4 * h;   // kv_local within sub-tile
          if (ro > qloc) s0[reg] = -1e30f;
          if (ro + 32 > qloc) s1[reg] = -1e30f;
        }
      }
      // ---- online softmax (row is lane-local) ----
      float tm[16];
#pragma unroll
      for (int i = 0; i < 16; ++i) tm[i] = fmaxf(s0[i], s1[i]);
#pragma unroll
      for (int off = 8; off >= 1; off >>= 1)
#pragma unroll
        for (int i = 0; i < off; ++i) tm[i] = fmaxf(tm[i], tm[i + off]);
      float rmax = fmaxf(tm[0], __shfl_xor(tm[0], 32));
      float mnew = fmaxf(mrow, rmax);
      float osc = __expf(mrow - mnew);
      bool need = __any(mnew > mrow);
#pragma unroll
      for (int i = 0; i < 16; ++i) {
        s0[i] = __expf(s0[i] - mnew);
        s1[i] = __expf(s1[i] - mnew);
      }
      float ts[16];
#pragma unroll
      for (int i = 0; i < 16; ++i) ts[i] = s0[i] + s1[i];
#pragma unroll
      for (int off = 8; off >= 1; off >>= 1)
#pragma unroll
        for (int i = 0; i < off; ++i) ts[i] += ts[i + off];
      float rsum = ts[0] + __shfl_xor(ts[0], 32);
      if (need) {
#pragma unroll
        for (int reg = 0; reg < 16; ++reg) {
          int rs = (reg & 3) + 8 * (reg >> 2) + 4 * h;
          float o = __shfl(osc, rs);
          acc0[reg] *= o;
          acc1[reg] *= o;
        }
      }
      lrow = lrow * osc + rsum;
      mrow = mnew;
      // ---- in-register P -> A-fragment repack ----
      unsigned W0[4][2], W1[4][2], X0[4][2], X1[4][2];
#pragma unroll
      for (int sp = 0; sp < 4; ++sp)
#pragma unroll
        for (int u = 0; u < 2; ++u) {
          W0[sp][u] = packw(s0[sp * 4 + 2 * u], s0[sp * 4 + 2 * u + 1]);
          W1[sp][u] = packw(s1[sp * 4 + 2 * u], s1[sp * 4 + 2 * u + 1]);
        }
#pragma unroll
      for (int sp = 0; sp < 4; ++sp)
#pragma unroll
        for (int u = 0; u < 2; ++u) {
          X0[sp][u] = (unsigned)__shfl_xor((int)W0[sp][u], 32);
          X1[sp][u] = (unsigned)__shfl_xor((int)W1[sp][u], 32);
        }
      // ---- PV ----
      const char* Vt = (const char*)Vs[cur];
#pragma unroll
      for (int ks = 0; ks < 4; ++ks) {
        const unsigned (*W)[2] = (ks < 2) ? W0 : W1;
        const unsigned (*X)[2] = (ks < 2) ? X0 : X1;
        const int c = ks & 1;
        unsigned m0 = h ? X[2 * c + 1][0] : W[2 * c][0];
        unsigned m1 = h ? X[2 * c + 1][1] : W[2 * c][1];
        unsigned m2 = h ? W[2 * c + 1][0] : X[2 * c][0];
        unsigned m3 = h ? W[2 * c + 1][1] : X[2 * c][1];
        u32x4 pw = {m0, m1, m2, m3};
        bf16x8 pf = __builtin_bit_cast(bf16x8, pw);
        bf16x8 vf0 = frag64(Vt, l31, ks * 32 + h * 16);
        bf16x8 vf1 = frag64(Vt, 32 + l31, ks * 32 + h * 16);
        acc0 = __builtin_amdgcn_mfma_f32_32x32x16_bf16(pf, vf0, acc0, 0, 0, 0);
        acc1 = __builtin_amdgcn_mfma_f32_32x32x16_bf16(pf, vf1, acc1, 0, 0, 0);
      }
    }
    __syncthreads();
  }

  // ---- normalize + write: O[q0w + row][d], row = (reg&3)+8*(reg>>2)+4h ----
#pragma unroll
  for (int reg = 0; reg < 16; ++reg) {
    int rs = (reg & 3) + 8 * (reg >> 2) + 4 * h;
    float li = __shfl(lrow, rs);
    size_t base = ((size_t)bh * SEQ + q0w + rs) * HD;
    att[base + l31]      = (bf16)(acc0[reg] / li);
    att[base + 32 + l31] = (bf16)(acc1[reg] / li);
  }
}

extern "C" void kernel_launch(void* const* d_in, const int* in_sizes, int n_in,
                              void* d_out, int out_size, void* d_ws, size_t ws_size,
                              hipStream_t stream) {
  const float* x  = (const float*)d_in[0];
  const int* pos  = (const int*)d_in[1];
  const float* Wq = (const float*)d_in[2];
  const float* Wk = (const float*)d_in[3];
  const float* Wv = (const float*)d_in[4];
  const float* Wo = (const float*)d_in[5];
  float* out = (float*)d_out;

  char* p = (char*)d_ws;
  bf16* xb   = (bf16*)p; p += (size_t)MTOT * DM * 2;
  bf16* wqb  = (bf16*)p; p += (size_t)DM * DM * 2;
  bf16* wkb  = (bf16*)p; p += (size_t)DM * DM * 2;
  bf16* wvb  = (bf16*)p; p += (size_t)DM * DM * 2;
  bf16* wob  = (bf16*)p; p += (size_t)DM * DM * 2;
  bf16* qb   = (bf16*)p; p += (size_t)MTOT * DM * 2;
  bf16* kb   = (bf16*)p; p += (size_t)MTOT * DM * 2;
  bf16* vtb  = (bf16*)p; p += (size_t)MTOT * DM * 2;
  bf16* attb = (bf16*)p; p += (size_t)MTOT * DM * 2;
  float2* tab = (float2*)p; p += (size_t)MTOT * 32 * sizeof(float2);

  cvt_kernel<<<(MTOT * DM / 4 + 255) / 256, 256, 0, stream>>>(x, xb, MTOT * DM / 4);
  cvt4_kernel<<<(4 * 262144 + 255) / 256, 256, 0, stream>>>(Wq, Wk, Wv, Wo, wqb);
  rope_tab_kernel<<<(MTOT * 32 + 255) / 256, 256, 0, stream>>>(pos, tab);

  gemm_qkv<<<dim3(24, MTOT / 128), 256, 0, stream>>>(xb, wqb, wkb, wvb, qb, kb, vtb, tab);

  attn_kernel<<<dim3(16, 2 * NH), 256, 0, stream>>>(qb, kb, vtb, attb);

  gemm_out<<<dim3(DM / 128, MTOT / 128), 256, 0, stream>>>(attb, wob, out);
}

// Round 4
// 160.749 us; speedup vs baseline: 2.4758x; 1.0861x over previous
//
#include <hip/hip_runtime.h>
#include <hip/hip_bf16.h>

typedef __bf16 bf16;
typedef __bf16 bf16x4 __attribute__((ext_vector_type(4)));
typedef __bf16 bf16x8 __attribute__((ext_vector_type(8)));
typedef float f32x4 __attribute__((ext_vector_type(4)));
typedef float f32x16 __attribute__((ext_vector_type(16)));
typedef unsigned int u32x4 __attribute__((ext_vector_type(4)));

#define NH 16
#define HD 64
#define SEQ 2048
#define DM 1024
#define MTOT 4096   // B*S

__device__ __forceinline__ void gload_lds16(const void* g, void* l) {
  __builtin_amdgcn_global_load_lds(
      (const __attribute__((address_space(1))) void*)g,
      (__attribute__((address_space(3))) void*)l, 16, 0, 0);
}

// ---------------- fp32 -> bf16 conversion (vectorized) ----------------
__global__ void cvt_kernel(const float* __restrict__ in, bf16* __restrict__ out, int n4) {
  int i = blockIdx.x * blockDim.x + threadIdx.x;
  if (i >= n4) return;
  float4 v = reinterpret_cast<const float4*>(in)[i];
  bf16x4 o;
  o[0] = (bf16)v.x; o[1] = (bf16)v.y; o[2] = (bf16)v.z; o[3] = (bf16)v.w;
  *reinterpret_cast<bf16x4*>(out + (size_t)i * 4) = o;
}

// 4 weight matrices (1M elems each) -> contiguous bf16 out
__global__ void cvt4_kernel(const float* __restrict__ w0, const float* __restrict__ w1,
                            const float* __restrict__ w2, const float* __restrict__ w3,
                            bf16* __restrict__ out) {
  int i = blockIdx.x * blockDim.x + threadIdx.x;   // 0 .. 4*262144-1
  int seg = i >> 18;
  int j = i & 262143;
  const float* src = seg == 0 ? w0 : seg == 1 ? w1 : seg == 2 ? w2 : w3;
  float4 v = reinterpret_cast<const float4*>(src)[j];
  bf16x4 o;
  o[0] = (bf16)v.x; o[1] = (bf16)v.y; o[2] = (bf16)v.z; o[3] = (bf16)v.w;
  *reinterpret_cast<bf16x4*>(out + ((size_t)seg << 20) + (size_t)j * 4) = o;
}

// ---------------- RoPE cos/sin table: tab[m][i2] = (cos, sin) ----------------
__global__ void rope_tab_kernel(const int* __restrict__ pos, float2* __restrict__ tab) {
  int i = blockIdx.x * blockDim.x + threadIdx.x;
  if (i >= MTOT * 32) return;
  int m = i >> 5, i2 = i & 31;
  float pf = (float)pos[m];
  float inv = 1.0f / powf(10000.0f, (float)(2 * i2) * (1.0f / 64.0f));
  float a = pf * inv;
  tab[i] = make_float2(cosf(a), sinf(a));
}

// ---------------- fused QKV projection GEMM ----------------
// blockIdx.x in 0..23: proj = x>>3 (0=Q,1=K,2=V), n0 = (x&7)*128.
// Q: RoPE + 0.125*log2e scale (attn works in exp2 domain) -> [B,H,S,hd]
// K: RoPE -> [B,H,S,hd]; V: -> [B,H,hd,S]
__global__ __launch_bounds__(256) void gemm_qkv(
    const bf16* __restrict__ A, const bf16* __restrict__ wq,
    const bf16* __restrict__ wk, const bf16* __restrict__ wv,
    bf16* __restrict__ outq, bf16* __restrict__ outk, bf16* __restrict__ outv,
    const float2* __restrict__ tab)
{
  __shared__ bf16 As[128 * 32];
  __shared__ bf16 Bs[128 * 32];
  const int t = threadIdx.x;
  const int w = t >> 6;
  const int lane = t & 63;
  const int lr = lane & 15;
  const int lg = lane >> 4;
  const int lk = lg << 3;
  const int m0 = blockIdx.y * 128;
  const int proj = blockIdx.x >> 3;
  const int n0 = (blockIdx.x & 7) * 128;
  const bf16* Bw = proj == 0 ? wq : proj == 1 ? wk : wv;
  const int wr = w >> 1, wc = w & 1;

  f32x4 acc[4][4] = {};

  for (int k0 = 0; k0 < DM; k0 += 32) {
#pragma unroll
    for (int pp = 0; pp < 2; ++pp) {
      int chunk = pp * 256 + t;
      int r = chunk >> 2;
      int c = (chunk & 3) << 3;
      gload_lds16(A + (size_t)(m0 + r) * DM + k0 + c, (char*)As + (pp * 256 + w * 64) * 16);
      gload_lds16(Bw + (size_t)(n0 + r) * DM + k0 + c, (char*)Bs + (pp * 256 + w * 64) * 16);
    }
    __syncthreads();
    bf16x8 af[4], bfr[4];
#pragma unroll
    for (int f = 0; f < 4; ++f) {
      af[f]  = *reinterpret_cast<const bf16x8*>(As + (wr * 64 + f * 16 + lr) * 32 + lk);
      bfr[f] = *reinterpret_cast<const bf16x8*>(Bs + (wc * 64 + f * 16 + lr) * 32 + lk);
    }
#pragma unroll
    for (int i = 0; i < 4; ++i)
#pragma unroll
      for (int j = 0; j < 4; ++j)
        acc[i][j] = __builtin_amdgcn_mfma_f32_16x16x32_bf16(af[i], bfr[j], acc[i][j], 0, 0, 0);
    __syncthreads();
  }

  if (proj < 2) {
    bf16* outb = proj ? outk : outq;
#pragma unroll
    for (int j = 0; j < 4; ++j) {
      int n = n0 + wc * 64 + j * 16 + lr;
      int h = n >> 6, d = n & 63;
      int i2 = d >> 1;
      bool odd = d & 1;
#pragma unroll
      for (int i = 0; i < 4; ++i) {
#pragma unroll
        for (int rr = 0; rr < 4; ++rr) {
          int m = m0 + wr * 64 + i * 16 + lg * 4 + rr;
          float v = acc[i][j][rr];
          float o = __shfl_xor(v, 1);
          float2 cs = tab[(m << 5) + i2];
          float res = odd ? (v * cs.x + o * cs.y) : (v * cs.x - o * cs.y);
          if (proj == 0) res *= 0.125f * 1.44269504f;   // 1/sqrt(hd) * log2(e)
          outb[((size_t)((m >> 11) * NH + h) * SEQ + (m & 2047)) * HD + d] = (bf16)res;
        }
      }
    }
  } else {
#pragma unroll
    for (int j = 0; j < 4; ++j) {
      int n = n0 + wc * 64 + j * 16 + lr;
      int h = n >> 6, d = n & 63;
#pragma unroll
      for (int i = 0; i < 4; ++i) {
#pragma unroll
        for (int rr = 0; rr < 4; ++rr) {
          int m = m0 + wr * 64 + i * 16 + lg * 4 + rr;
          outv[((size_t)((m >> 11) * NH + h) * HD + d) * SEQ + (m & 2047)] = (bf16)acc[i][j][rr];
        }
      }
    }
  }
}

// ---------------- output projection GEMM (A from att [B,H,S,hd]) ----------------
__global__ __launch_bounds__(256) void gemm_out(
    const bf16* __restrict__ A, const bf16* __restrict__ Bw, float* __restrict__ outf)
{
  __shared__ bf16 As[128 * 32];
  __shared__ bf16 Bs[128 * 32];
  const int t = threadIdx.x;
  const int w = t >> 6;
  const int lane = t & 63;
  const int lr = lane & 15;
  const int lg = lane >> 4;
  const int lk = lg << 3;
  const int m0 = blockIdx.y * 128;
  const int n0 = blockIdx.x * 128;
  const int wr = w >> 1, wc = w & 1;

  f32x4 acc[4][4] = {};

  for (int k0 = 0; k0 < DM; k0 += 32) {
#pragma unroll
    for (int pp = 0; pp < 2; ++pp) {
      int chunk = pp * 256 + t;
      int r = chunk >> 2;
      int c = (chunk & 3) << 3;
      int m = m0 + r;
      int kk = k0 + c;
      const bf16* ga = A + (((size_t)((m >> 11) * NH + (kk >> 6)) * SEQ + (m & 2047)) * HD + (kk & 63));
      gload_lds16(ga, (char*)As + (pp * 256 + w * 64) * 16);
      gload_lds16(Bw + (size_t)(n0 + r) * DM + k0 + c, (char*)Bs + (pp * 256 + w * 64) * 16);
    }
    __syncthreads();
    bf16x8 af[4], bfr[4];
#pragma unroll
    for (int f = 0; f < 4; ++f) {
      af[f]  = *reinterpret_cast<const bf16x8*>(As + (wr * 64 + f * 16 + lr) * 32 + lk);
      bfr[f] = *reinterpret_cast<const bf16x8*>(Bs + (wc * 64 + f * 16 + lr) * 32 + lk);
    }
#pragma unroll
    for (int i = 0; i < 4; ++i)
#pragma unroll
      for (int j = 0; j < 4; ++j)
        acc[i][j] = __builtin_amdgcn_mfma_f32_16x16x32_bf16(af[i], bfr[j], acc[i][j], 0, 0, 0);
    __syncthreads();
  }

#pragma unroll
  for (int j = 0; j < 4; ++j) {
    int n = n0 + wc * 64 + j * 16 + lr;
#pragma unroll
    for (int i = 0; i < 4; ++i) {
#pragma unroll
      for (int rr = 0; rr < 4; ++rr) {
        int m = m0 + wr * 64 + i * 16 + lg * 4 + rr;
        outf[(size_t)m * DM + n] = acc[i][j][rr];
      }
    }
  }
}

// ---------------- flash attention ----------------
// 1-D grid, 512 blocks of 256 threads. Block covers strips 2j (waves 0,1) and
// 2j+1 (waves 2,3) of one bh => tile needs differ by 1, idle ~1 iter/block.
// Complementary idx mapping: blocks idx and idx+256 have j summing to 15, so
// co-resident blocks on a CU sum to a constant workload (perf heuristic only).
// Counted-vmcnt double-buffer: next-tile global_load_lds stays in flight
// across raw s_barrier (no vmcnt(0) drain).
__device__ __forceinline__ void stage_tile(const char* gRow0, size_t rowStrideB, int colByte0,
                                           char* lds, int t) {
#pragma unroll
  for (int p = 0; p < 2; ++p) {
    int o = (p * 256 + t) * 16;
    int r = o >> 7;
    int cb = o & 127;
    int cbs = cb ^ ((r & 7) << 4);
    gload_lds16(gRow0 + (size_t)r * rowStrideB + colByte0 + cbs, lds + o);
  }
}

__device__ __forceinline__ bf16x8 frag64(const char* tile, int row, int colByte) {
  int b = row * 128 + (colByte ^ ((row & 7) << 4));
  return *reinterpret_cast<const bf16x8*>(tile + b);
}

__device__ __forceinline__ unsigned packw(float a, float b) {
  unsigned short la = __builtin_bit_cast(unsigned short, (bf16)a);
  unsigned short lb = __builtin_bit_cast(unsigned short, (bf16)b);
  return (unsigned)la | ((unsigned)lb << 16);
}

__global__ __launch_bounds__(256) void attn_kernel(
    const bf16* __restrict__ q, const bf16* __restrict__ k,
    const bf16* __restrict__ vt, bf16* __restrict__ att)
{
  __shared__ bf16 Ks[2][64 * 64];
  __shared__ bf16 Vs[2][64 * 64];
  const int t = threadIdx.x;
  const int w = t >> 6;
  const int lane = t & 63;
  const int l31 = lane & 31;
  const int h = lane >> 5;

  // decode (j, bh) with complementary pairing
  const int idx = blockIdx.x;
  const int half = idx >> 8;
  const int sub = idx & 255;
  const int bh = sub & 31;
  const int j = half ? (sub >> 5) : (15 - (sub >> 5));

  const int strip = 2 * j + (w >> 1);      // this wave's 64-row strip
  const int myN = strip + 1;               // kv tiles this wave computes
  const int blkN = 2 * j + 2;              // tiles staged by the block
  const int q0w = j * 128 + w * 32;        // this wave's 32 q-rows

  const bf16* qb = q + (size_t)bh * SEQ * HD;
  const char* kbB = (const char*)(k + (size_t)bh * SEQ * HD);
  const char* vbB = (const char*)(vt + (size_t)bh * HD * SEQ);

  // Q fragments (B operand of 32x32x16): qf[s] = Q[q0w+l31][s*16 + h*8 .. +7]
  bf16x8 qf[4];
#pragma unroll
  for (int s = 0; s < 4; ++s)
    qf[s] = *reinterpret_cast<const bf16x8*>(qb + (size_t)(q0w + l31) * HD + s * 16 + h * 8);

  f32x16 acc0 = {}, acc1 = {};
  float mrow = -1e30f, lrow = 0.f;

  stage_tile(kbB, 128, 0, (char*)Ks[0], t);
  stage_tile(vbB, 4096, 0, (char*)Vs[0], t);

  for (int it = 0; it < blkN; ++it) {
    const int cur = it & 1;
    if (it + 1 < blkN) {
      stage_tile(kbB + (size_t)(it + 1) * 8192, 128, 0, (char*)Ks[cur ^ 1], t);
      stage_tile(vbB, 4096, (it + 1) * 128, (char*)Vs[cur ^ 1], t);
      asm volatile("s_waitcnt vmcnt(4)" ::: "memory");   // tile `it` arrived; next stays in flight
    } else {
      asm volatile("s_waitcnt vmcnt(0)" ::: "memory");
    }
    __builtin_amdgcn_sched_barrier(0);
    __builtin_amdgcn_s_barrier();          // tile `it` visible to all waves

    if (it < myN) {
      const char* Kt = (const char*)Ks[cur];
      // ---- S^T = mfma(K, Q): lane holds S[q=q0w+l31][kv 32 values], log2 domain ----
      f32x16 s0 = {}, s1 = {};
#pragma unroll
      for (int s = 0; s < 4; ++s) {
        bf16x8 kf0 = frag64(Kt, l31, s * 32 + h * 16);
        bf16x8 kf1 = frag64(Kt, 32 + l31, s * 32 + h * 16);
        s0 = __builtin_amdgcn_mfma_f32_32x32x16_bf16(kf0, qf[s], s0, 0, 0, 0);
        s1 = __builtin_amdgcn_mfma_f32_32x32x16_bf16(kf1, qf[s], s1, 0, 0, 0);
      }
      // ---- causal mask (diagonal tile only): kv_local > q_local ----
      if (it == strip) {
        int qloc = (w & 1) * 32 + l31;
#pragma unroll
        for (int reg = 0; reg < 16; ++reg) {
          int ro = (reg & 3) + 8 * (reg >> 2) + 4 * h;   // kv_local within sub-tile
          if (ro > qloc) s0[reg] = -1e30f;
          if (ro + 32 > qloc) s1[reg] = -1e30f;
        }
      }
      // ---- online softmax (row lane-local), defer-max (T13), exp2 domain ----
      float tm[16];
#pragma unroll
      for (int i = 0; i < 16; ++i) tm[i] = fmaxf(s0[i], s1[i]);
#pragma unroll
      for (int off = 8; off >= 1; off >>= 1)
#pragma unroll
        for (int i = 0; i < off; ++i) tm[i] = fmaxf(tm[i], tm[i + off]);
      float rmax = fmaxf(tm[0], __shfl_xor(tm[0], 32));

      bool need = __any(rmax > mrow + 11.5f);   // 11.5 = 8/ln2-ish headroom in log2 domain
      if (need) {
        float mnew = fmaxf(mrow, rmax);
        float osc = exp2f(mrow - mnew);
#pragma unroll
        for (int reg = 0; reg < 16; ++reg) {
          int rs = (reg & 3) + 8 * (reg >> 2) + 4 * h;
          float o = __shfl(osc, rs);
          acc0[reg] *= o;
          acc1[reg] *= o;
        }
        lrow *= osc;
        mrow = mnew;
      }
#pragma unroll
      for (int i = 0; i < 16; ++i) {
        s0[i] = exp2f(s0[i] - mrow);
        s1[i] = exp2f(s1[i] - mrow);
      }
      float ts[16];
#pragma unroll
      for (int i = 0; i < 16; ++i) ts[i] = s0[i] + s1[i];
#pragma unroll
      for (int off = 8; off >= 1; off >>= 1)
#pragma unroll
        for (int i = 0; i < off; ++i) ts[i] += ts[i + off];
      lrow += ts[0] + __shfl_xor(ts[0], 32);

      // ---- in-register P -> A-fragment repack ----
      unsigned W0[4][2], W1[4][2], X0[4][2], X1[4][2];
#pragma unroll
      for (int sp = 0; sp < 4; ++sp)
#pragma unroll
        for (int u = 0; u < 2; ++u) {
          W0[sp][u] = packw(s0[sp * 4 + 2 * u], s0[sp * 4 + 2 * u + 1]);
          W1[sp][u] = packw(s1[sp * 4 + 2 * u], s1[sp * 4 + 2 * u + 1]);
        }
#pragma unroll
      for (int sp = 0; sp < 4; ++sp)
#pragma unroll
        for (int u = 0; u < 2; ++u) {
          X0[sp][u] = (unsigned)__shfl_xor((int)W0[sp][u], 32);
          X1[sp][u] = (unsigned)__shfl_xor((int)W1[sp][u], 32);
        }
      // ---- PV ----
      const char* Vt = (const char*)Vs[cur];
#pragma unroll
      for (int ks = 0; ks < 4; ++ks) {
        const unsigned (*W)[2] = (ks < 2) ? W0 : W1;
        const unsigned (*X)[2] = (ks < 2) ? X0 : X1;
        const int c = ks & 1;
        unsigned m0 = h ? X[2 * c + 1][0] : W[2 * c][0];
        unsigned m1 = h ? X[2 * c + 1][1] : W[2 * c][1];
        unsigned m2 = h ? W[2 * c + 1][0] : X[2 * c][0];
        unsigned m3 = h ? W[2 * c + 1][1] : X[2 * c][1];
        u32x4 pw = {m0, m1, m2, m3};
        bf16x8 pf = __builtin_bit_cast(bf16x8, pw);
        bf16x8 vf0 = frag64(Vt, l31, ks * 32 + h * 16);
        bf16x8 vf1 = frag64(Vt, 32 + l31, ks * 32 + h * 16);
        acc0 = __builtin_amdgcn_mfma_f32_32x32x16_bf16(pf, vf0, acc0, 0, 0, 0);
        acc1 = __builtin_amdgcn_mfma_f32_32x32x16_bf16(pf, vf1, acc1, 0, 0, 0);
      }
    }
    __builtin_amdgcn_s_barrier();          // all waves done reading tile `it`
  }

  // ---- normalize + write: O[q0w + row][d], row = (reg&3)+8*(reg>>2)+4h ----
#pragma unroll
  for (int reg = 0; reg < 16; ++reg) {
    int rs = (reg & 3) + 8 * (reg >> 2) + 4 * h;
    float li = __shfl(lrow, rs);
    size_t base = ((size_t)bh * SEQ + q0w + rs) * HD;
    att[base + l31]      = (bf16)(acc0[reg] / li);
    att[base + 32 + l31] = (bf16)(acc1[reg] / li);
  }
}

extern "C" void kernel_launch(void* const* d_in, const int* in_sizes, int n_in,
                              void* d_out, int out_size, void* d_ws, size_t ws_size,
                              hipStream_t stream) {
  const float* x  = (const float*)d_in[0];
  const int* pos  = (const int*)d_in[1];
  const float* Wq = (const float*)d_in[2];
  const float* Wk = (const float*)d_in[3];
  const float* Wv = (const float*)d_in[4];
  const float* Wo = (const float*)d_in[5];
  float* out = (float*)d_out;

  char* p = (char*)d_ws;
  bf16* xb   = (bf16*)p; p += (size_t)MTOT * DM * 2;
  bf16* wqb  = (bf16*)p; p += (size_t)DM * DM * 2;
  bf16* wkb  = (bf16*)p; p += (size_t)DM * DM * 2;
  bf16* wvb  = (bf16*)p; p += (size_t)DM * DM * 2;
  bf16* wob  = (bf16*)p; p += (size_t)DM * DM * 2;
  bf16* qb   = (bf16*)p; p += (size_t)MTOT * DM * 2;
  bf16* kb   = (bf16*)p; p += (size_t)MTOT * DM * 2;
  bf16* vtb  = (bf16*)p; p += (size_t)MTOT * DM * 2;
  bf16* attb = (bf16*)p; p += (size_t)MTOT * DM * 2;
  float2* tab = (float2*)p; p += (size_t)MTOT * 32 * sizeof(float2);

  cvt_kernel<<<(MTOT * DM / 4 + 255) / 256, 256, 0, stream>>>(x, xb, MTOT * DM / 4);
  cvt4_kernel<<<(4 * 262144 + 255) / 256, 256, 0, stream>>>(Wq, Wk, Wv, Wo, wqb);
  rope_tab_kernel<<<(MTOT * 32 + 255) / 256, 256, 0, stream>>>(pos, tab);

  gemm_qkv<<<dim3(24, MTOT / 128), 256, 0, stream>>>(xb, wqb, wkb, wvb, qb, kb, vtb, tab);

  attn_kernel<<<512, 256, 0, stream>>>(qb, kb, vtb, attb);

  gemm_out<<<dim3(DM / 128, MTOT / 128), 256, 0, stream>>>(attb, wob, out);
}